// Round 5
// baseline (182.278 us; speedup 1.0000x reference)
//
#include <hip/hip_runtime.h>
#include <hip/hip_cooperative_groups.h>

namespace cg = cooperative_groups;

// Problem constants (fixed by reference setup_inputs)
#define BB 4
#define LL 4096
#define MM 1024
#define DD 2048
#define SEG 32
#define SM 32          // MM / SEG
#define SEGSHIFT 5

typedef float f32x4 __attribute__((ext_vector_type(4)));

// ---------------------------------------------------------------------------
// Kernel A: per-batch prep.
//  - block-wide cumsum of boundary_mask over L=4096 (1024 thr x 4 elems)
//  - scatter clipped p into p_chunked (stable partition: boundary first)
//  - chunk_idx[b,l] = clip(incl_cumsum-1, 0, M-1)
//  - Ppref[b,t] = in-segment (32-wide) inclusive prefix product of a[t],
//    a[0]=0, a[t]=1-p[t].  (Pseg[s] = Ppref[s*32+31].)
// ---------------------------------------------------------------------------
__global__ __launch_bounds__(1024) void prep_kernel(
    const float* __restrict__ bprob,   // (B, L, 2)
    const int*   __restrict__ bmask,   // (B, L) 0/1
    float* __restrict__ p_chunked,     // (B, M)
    int*   __restrict__ chunk_idx,     // (B, L)
    float* __restrict__ Ppref)         // (B, M)
{
    const int b   = blockIdx.x;
    const int tid = threadIdx.x;
    const int lane = tid & 63;
    const int wid  = tid >> 6;

    __shared__ int wsum[16];
    __shared__ int s_total;

    int4 mv = reinterpret_cast<const int4*>(bmask + b * LL)[tid];
    int ms[4] = { mv.x, mv.y, mv.z, mv.w };
    int s = ms[0] + ms[1] + ms[2] + ms[3];

    int v = s;
    #pragma unroll
    for (int off = 1; off < 64; off <<= 1) {
        int u = __shfl_up(v, off, 64);
        if (lane >= off) v += u;
    }
    if (lane == 63) wsum[wid] = v;
    __syncthreads();
    if (tid == 0) {
        int acc = 0;
        #pragma unroll
        for (int w = 0; w < 16; ++w) { int t = wsum[w]; wsum[w] = acc; acc += t; }
        s_total = acc;
    }
    __syncthreads();

    const int NB = s_total;
    int e = (v - s) + wsum[wid];

    const int base_l = tid * 4;
    #pragma unroll
    for (int j = 0; j < 4; ++j) {
        int l = base_l + j;
        int m = ms[j];
        int incl = e + m;
        int ci = incl - 1;
        ci = ci < 0 ? 0 : (ci > MM - 1 ? MM - 1 : ci);
        chunk_idx[b * LL + l] = ci;
        int pos = m ? e : (NB + (l - e));
        if (pos < MM) {
            float p = bprob[((size_t)b * LL + l) * 2 + 1];
            p = fminf(fmaxf(p, 1e-4f), 1.0f - 1e-4f);
            p_chunked[b * MM + pos] = p;
        }
        e = incl;
    }
    __syncthreads();

    {
        int t = tid;
        float p = p_chunked[b * MM + t];
        float a = (t == 0) ? 0.0f : (1.0f - p);
        float pr = a;
        #pragma unroll
        for (int off = 1; off < 32; off <<= 1) {
            float u = __shfl_up(pr, off, 32);
            if ((t & 31) >= off) pr *= u;
        }
        Ppref[b * MM + t] = pr;
    }
}

// ---------------------------------------------------------------------------
// Cooperative kernel: scan (local in REGISTERS) -> grid.sync -> carry fixup
// -> corrected y write -> grid.sync -> balanced gather.
// grid = (D/512, SEG, B) = (4, 32, 4) = 512 blocks, block = 256.
// ---------------------------------------------------------------------------
__global__ __launch_bounds__(256) void coop_kernel(
    const float* __restrict__ x,          // (B, M, D)
    const float* __restrict__ p_chunked,  // (B, M)
    const float* __restrict__ Ppref,      // (B, M)
    float* __restrict__ seglast,          // (B, SEG, D)
    float* __restrict__ y,                // (B, M, D)
    const int* __restrict__ chunk_idx,    // (B, L)
    float* __restrict__ out)              // (B, L, D)
{
    cg::grid_group grid = cg::this_grid();

    const int dsl = blockIdx.x;          // d-slice of 512 floats
    const int seg = blockIdx.y;
    const int b   = blockIdx.z;
    const int tid = threadIdx.x;
    const int d0  = dsl * 512 + tid * 2;
    const int t0  = seg * SM;

    __shared__ float sp[SM];
    __shared__ float spp[SM];
    if (tid < SM) {
        sp[tid]  = p_chunked[b * MM + t0 + tid];
        spp[tid] = Ppref[b * MM + t0 + tid];
    }
    __syncthreads();

    // ---- phase 1: local segment scan, values kept in registers ----
    float2 yl[SM];
    float2 prev = make_float2(0.0f, 0.0f);
    const size_t base = ((size_t)b * MM + t0) * DD + d0;
    #pragma unroll
    for (int i = 0; i < SM; ++i) {
        float p = sp[i];
        bool first = (seg == 0) && (i == 0);
        float ac = first ? 0.0f : (1.0f - p);
        float bc = first ? 1.0f : p;
        float2 xt = *reinterpret_cast<const float2*>(x + base + (size_t)i * DD);
        prev.x = fmaf(ac, prev.x, bc * xt.x);
        prev.y = fmaf(ac, prev.y, bc * xt.y);
        yl[i] = prev;
    }
    *reinterpret_cast<float2*>(seglast + ((size_t)b * SEG + seg) * DD + d0) = prev;

    grid.sync();

    // ---- phase 2: carry-in from predecessor segments, then corrected y ----
    float2 carry = make_float2(0.0f, 0.0f);
    for (int s = 0; s < seg; ++s) {
        float Pf = Ppref[b * MM + s * SM + SM - 1];   // uniform scalar
        float2 lv = *reinterpret_cast<const float2*>(
            seglast + ((size_t)b * SEG + s) * DD + d0);
        carry.x = fmaf(Pf, carry.x, lv.x);
        carry.y = fmaf(Pf, carry.y, lv.y);
    }

    #pragma unroll
    for (int i = 0; i < SM; ++i) {
        float Pp = spp[i];
        float2 v;
        v.x = fmaf(Pp, carry.x, yl[i].x);
        v.y = fmaf(Pp, carry.y, yl[i].y);
        *reinterpret_cast<float2*>(y + base + (size_t)i * DD) = v;
    }

    grid.sync();

    // ---- phase 3: balanced gather. Block handles 128 rows x its d-slice ----
    // rows l in [seg*128, seg*128+128) of batch b (blockIdx.y reused).
    const int j    = tid & 127;          // vec4 index within 512-float slice
    const int half = tid >> 7;           // 2 rows per iteration
    const int lbase = seg * 128;
    #pragma unroll 4
    for (int it = 0; it < 64; ++it) {
        int l = lbase + it * 2 + half;
        int t = chunk_idx[b * LL + l];
        const f32x4* src = reinterpret_cast<const f32x4*>(
            y + ((size_t)b * MM + t) * DD + dsl * 512);
        f32x4* dst = reinterpret_cast<f32x4*>(
            out + ((size_t)b * LL + l) * DD + dsl * 512);
        __builtin_nontemporal_store(src[j], &dst[j]);
    }
}

// ---------------------------------------------------------------------------
extern "C" void kernel_launch(void* const* d_in, const int* in_sizes, int n_in,
                              void* d_out, int out_size, void* d_ws, size_t ws_size,
                              hipStream_t stream) {
    const float* x     = (const float*)d_in[0];   // chunked_states (B,M,D) f32
    const float* bprob = (const float*)d_in[1];   // boundary_prob  (B,L,2) f32
    const int*   bmask = (const int*)d_in[2];     // boundary_mask  (B,L) int

    float* out = (float*)d_out;

    // workspace layout
    float* y         = (float*)d_ws;                          // B*M*D
    float* p_chunked = y + (size_t)BB * MM * DD;              // B*M
    float* Ppref     = p_chunked + BB * MM;                   // B*M
    float* seglast   = Ppref + BB * MM;                       // B*SEG*D
    int*   chunk_idx = (int*)(seglast + (size_t)BB * SEG * DD); // B*L

    prep_kernel<<<BB, 1024, 0, stream>>>(bprob, bmask, p_chunked, chunk_idx, Ppref);

    void* args[] = {
        (void*)&x, (void*)&p_chunked, (void*)&Ppref, (void*)&seglast,
        (void*)&y, (void*)&chunk_idx, (void*)&out
    };
    hipLaunchCooperativeKernel((const void*)coop_kernel,
                               dim3(DD / 512, SEG, BB), dim3(256),
                               args, 0, stream);
}

// Round 6
// 59.490 us; speedup vs baseline: 3.0640x; 3.0640x over previous
//
#include <hip/hip_runtime.h>
#include <hip/hip_bf16.h>

// Problem constants (fixed by reference setup_inputs)
#define BB 4
#define LL 4096
#define MM 1024
#define DD 2048
#define SEG 64
#define SM 16          // MM / SEG
#define SEGSHIFT 4

typedef float f32x4 __attribute__((ext_vector_type(4)));

// ---------------------------------------------------------------------------
// Kernel A: per-batch prep.
//  - block-wide cumsum of boundary_mask over L=4096 (1024 thr x 4 elems)
//  - scatter clipped p into p_chunked (stable partition: boundary first)
//  - chunk_idx[b,l] = clip(incl_cumsum-1, 0, M-1)
//  - Ppref[b,t] = in-segment (16-wide) inclusive prefix product of a[t],
//    a[0]=0, a[t]=1-p[t].  (Pseg[s] = Ppref[s*16+15].)
// ---------------------------------------------------------------------------
__global__ __launch_bounds__(1024) void prep_kernel(
    const float* __restrict__ bprob,   // (B, L, 2)
    const int*   __restrict__ bmask,   // (B, L) 0/1
    float* __restrict__ p_chunked,     // (B, M)
    int*   __restrict__ chunk_idx,     // (B, L)
    float* __restrict__ Ppref)         // (B, M)
{
    const int b   = blockIdx.x;
    const int tid = threadIdx.x;
    const int lane = tid & 63;
    const int wid  = tid >> 6;

    __shared__ int wsum[16];
    __shared__ int s_total;

    int4 mv = reinterpret_cast<const int4*>(bmask + b * LL)[tid];
    int ms[4] = { mv.x, mv.y, mv.z, mv.w };
    int s = ms[0] + ms[1] + ms[2] + ms[3];

    int v = s;
    #pragma unroll
    for (int off = 1; off < 64; off <<= 1) {
        int u = __shfl_up(v, off, 64);
        if (lane >= off) v += u;
    }
    if (lane == 63) wsum[wid] = v;
    __syncthreads();
    if (tid == 0) {
        int acc = 0;
        #pragma unroll
        for (int w = 0; w < 16; ++w) { int t = wsum[w]; wsum[w] = acc; acc += t; }
        s_total = acc;
    }
    __syncthreads();

    const int NB = s_total;
    int e = (v - s) + wsum[wid];

    const int base_l = tid * 4;
    #pragma unroll
    for (int j = 0; j < 4; ++j) {
        int l = base_l + j;
        int m = ms[j];
        int incl = e + m;
        int ci = incl - 1;
        ci = ci < 0 ? 0 : (ci > MM - 1 ? MM - 1 : ci);
        chunk_idx[b * LL + l] = ci;
        int pos = m ? e : (NB + (l - e));
        if (pos < MM) {
            float p = bprob[((size_t)b * LL + l) * 2 + 1];
            p = fminf(fmaxf(p, 1e-4f), 1.0f - 1e-4f);
            p_chunked[b * MM + pos] = p;
        }
        e = incl;
    }
    __syncthreads();

    // ---- in-segment prefix products over 16-wide segments: t = tid ----
    {
        int t = tid;
        float p = p_chunked[b * MM + t];
        float a = (t == 0) ? 0.0f : (1.0f - p);
        float pr = a;
        #pragma unroll
        for (int off = 1; off < SM; off <<= 1) {
            float u = __shfl_up(pr, off, SM);   // within 16-wide subgroups
            if ((t & (SM - 1)) >= off) pr *= u;
        }
        Ppref[b * MM + t] = pr;
    }
}

// ---------------------------------------------------------------------------
// Kernel B: segmented local EMA scan (zero initial carry per segment).
// grid = (D/1024, SEG, B) = (2, 64, 4) = 512 blocks, block = 256.
// One thread handles 4 consecutive d-channels (f32x4). Chain length 16,
// fully unrolled -> 16 independent 16B loads pipeline deep.
// Emits uncorrected local scan + compact seglast[b,seg,d].
// ---------------------------------------------------------------------------
__global__ __launch_bounds__(256) void scan_kernel(
    const float* __restrict__ x,          // (B, M, D)
    const float* __restrict__ p_chunked,  // (B, M)
    float* __restrict__ local,            // (B, M, D)
    float* __restrict__ seglast)          // (B, SEG, D)
{
    const int tid = threadIdx.x;
    const int d0  = blockIdx.x * 1024 + tid * 4;
    const int seg = blockIdx.y;
    const int b   = blockIdx.z;
    const int t0  = seg * SM;

    __shared__ float sp[SM];
    if (tid < SM) sp[tid] = p_chunked[b * MM + t0 + tid];
    __syncthreads();

    const size_t base = ((size_t)b * MM + t0) * DD + d0;

    f32x4 prev = {0.0f, 0.0f, 0.0f, 0.0f};
    #pragma unroll
    for (int i = 0; i < SM; ++i) {
        float p = sp[i];
        float ac, bc;
        if (i == 0) { ac = (seg == 0) ? 0.0f : (1.0f - p); bc = (seg == 0) ? 1.0f : p; }
        else        { ac = 1.0f - p; bc = p; }
        f32x4 xt = *reinterpret_cast<const f32x4*>(x + base + (size_t)i * DD);
        prev = ac * prev + bc * xt;
        *reinterpret_cast<f32x4*>(local + base + (size_t)i * DD) = prev;
    }
    *reinterpret_cast<f32x4*>(seglast + ((size_t)b * SEG + seg) * DD + d0) = prev;
}

// ---------------------------------------------------------------------------
// Kernel C: combine carries across the 64 segments, per (b, 4d).
// carry[b,seg,d] = true y at last element of segment seg-1 (0 for seg 0).
// Reads only the compact seglast buffer (2 MB, L2-resident).
// grid = 8 blocks x 256 threads (B*D/4 = 2048 threads).
// ---------------------------------------------------------------------------
__global__ __launch_bounds__(256) void carry_kernel(
    const float* __restrict__ seglast,    // (B, SEG, D)
    const float* __restrict__ Ppref,      // (B, M)
    float* __restrict__ carry)            // (B, SEG, D)
{
    int idx = blockIdx.x * 256 + threadIdx.x;   // over B*D/4
    int b  = idx >> 9;                           // D/4 = 512 per batch
    int d4 = (idx & 511) * 4;

    f32x4 run = {0.0f, 0.0f, 0.0f, 0.0f};
    #pragma unroll 16
    for (int s = 0; s < SEG; ++s) {
        *reinterpret_cast<f32x4*>(carry + ((size_t)b * SEG + s) * DD + d4) = run;
        f32x4 last = *reinterpret_cast<const f32x4*>(
            seglast + ((size_t)b * SEG + s) * DD + d4);
        float Pf = Ppref[b * MM + s * SM + SM - 1];   // uniform scalar
        run = Pf * run + last;
    }
}

// ---------------------------------------------------------------------------
// Kernel D: gather + carry fix-up fused.
// out[b,l,:] = local[b,t,:] + Ppref[b,t] * carry[b,seg(t),:], t = chunk_idx.
// 4 rows per block -> grid (L/4, B) = 4096 blocks; 8 independent
// load/store pairs per thread. nt stores keep local/carry rows in cache.
// ---------------------------------------------------------------------------
__global__ __launch_bounds__(256) void gather_kernel(
    const float* __restrict__ local,
    const float* __restrict__ Ppref,
    const float* __restrict__ carry,
    const int*   __restrict__ chunk_idx,
    float* __restrict__ out)              // (B, L, D)
{
    const int b   = blockIdx.y;
    const int l0  = blockIdx.x * 4;
    const int tid = threadIdx.x;

    #pragma unroll
    for (int r = 0; r < 4; ++r) {
        int l = l0 + r;
        int t = chunk_idx[b * LL + l];
        float W = Ppref[b * MM + t];
        int seg = t >> SEGSHIFT;

        const f32x4* lrow = reinterpret_cast<const f32x4*>(local + ((size_t)b * MM + t) * DD);
        const f32x4* crow = reinterpret_cast<const f32x4*>(carry + ((size_t)b * SEG + seg) * DD);
        f32x4* orow       = reinterpret_cast<f32x4*>(out + ((size_t)b * LL + l) * DD);

        #pragma unroll
        for (int k = 0; k < 2; ++k) {
            int i = tid + k * 256;        // 512 vec4 per row
            f32x4 ov = lrow[i] + W * crow[i];
            __builtin_nontemporal_store(ov, &orow[i]);
        }
    }
}

// ---------------------------------------------------------------------------
extern "C" void kernel_launch(void* const* d_in, const int* in_sizes, int n_in,
                              void* d_out, int out_size, void* d_ws, size_t ws_size,
                              hipStream_t stream) {
    const float* x     = (const float*)d_in[0];   // chunked_states (B,M,D) f32
    const float* bprob = (const float*)d_in[1];   // boundary_prob  (B,L,2) f32
    const int*   bmask = (const int*)d_in[2];     // boundary_mask  (B,L) int

    float* out = (float*)d_out;

    // workspace layout
    float* local     = (float*)d_ws;                          // B*M*D
    float* p_chunked = local + (size_t)BB * MM * DD;          // B*M
    float* Ppref     = p_chunked + BB * MM;                   // B*M
    float* seglast   = Ppref + BB * MM;                       // B*SEG*D
    float* carry     = seglast + (size_t)BB * SEG * DD;       // B*SEG*D
    int*   chunk_idx = (int*)(carry + (size_t)BB * SEG * DD); // B*L

    prep_kernel<<<BB, 1024, 0, stream>>>(bprob, bmask, p_chunked, chunk_idx, Ppref);
    scan_kernel<<<dim3(DD / 1024, SEG, BB), 256, 0, stream>>>(x, p_chunked, local, seglast);
    carry_kernel<<<(BB * DD / 4) / 256, 256, 0, stream>>>(seglast, Ppref, carry);
    gather_kernel<<<dim3(LL / 4, BB), 256, 0, stream>>>(local, Ppref, carry, chunk_idx, out);
}